// Round 18
// baseline (92.091 us; speedup 1.0000x reference)
//
#include <hip/hip_runtime.h>
#include <hip/hip_fp16.h>
#include <math.h>

// MPS-RNN 2D forward: L=8, M=8, DCUT=6, HL=2, N=64, B=32768
// Round-18 = round-17 with the VGPR cap removed (__launch_bounds__(256)):
// grid caps occupancy at 2 waves/SIMD anyway (2048 waves total), which is
// achievable up to 256 VGPR -- the (256,2) bound just forced scratch spill
// (WRITE_SIZE 128->640KB in r17). Register vertical state, fp16 VE, scalar
// W/C paths all retained.

#define NQ  64
#define BT  256
#define SPB 64

typedef _Float16 h2v __attribute__((ext_vector_type(2)));
typedef __fp16  p2v __attribute__((ext_vector_type(2)));
union H2U { unsigned u; h2v h; __half2 hh; };

static __device__ __forceinline__ h2v pack2(float a, float b) {
    p2v p = __builtin_amdgcn_cvt_pkrtz(a, b);
    h2v r; __builtin_memcpy(&r, &p, sizeof(r));
    return r;
}
static __device__ __forceinline__ h2v u2h(unsigned u) {
    h2v r; __builtin_memcpy(&r, &u, sizeof(r));
    return r;
}
static __device__ __forceinline__ unsigned h2u(h2v h) {
    unsigned r; __builtin_memcpy(&r, &h, sizeof(r));
    return r;
}

#define DPPF(x, ctrl) __int_as_float(__builtin_amdgcn_update_dpp(            \
    __float_as_int(x), __float_as_int(x), (ctrl), 0xF, 0xF, false))
#define QP_XOR1 0xB1   // quad_perm [1,0,3,2]
#define QP_XOR2 0x4E   // quad_perm [2,3,0,1]
#define QP_BC0  0x00
#define QP_BC1  0x55

#if defined(__has_builtin)
#  if __has_builtin(__builtin_amdgcn_rcpf)
#    define FAST_RCP(x) __builtin_amdgcn_rcpf(x)
#  else
#    define FAST_RCP(x) (1.0f / (x))
#  endif
#  if __has_builtin(__builtin_amdgcn_rsqf)
#    define FAST_RSQ(x) __builtin_amdgcn_rsqf(x)
#  else
#    define FAST_RSQ(x) rsqrtf(x)
#  endif
#  if __has_builtin(__builtin_amdgcn_fdot2)
#    define HAS_FDOT2 1
#  endif
#else
#  define FAST_RCP(x) (1.0f / (x))
#  define FAST_RSQ(x) rsqrtf(x)
#endif

static __device__ __forceinline__ float fdot2u(unsigned a, h2v b, float c) {
#ifdef HAS_FDOT2
    H2U u; u.u = a;
    return __builtin_amdgcn_fdot2(u.h, b, c, false);
#else
    H2U u; u.u = a;
    return fmaf((float)u.h.x, (float)b.x, fmaf((float)u.h.y, (float)b.y, c));
#endif
}

__global__ __launch_bounds__(BT) void mps_rnn18(
    const float* __restrict__ Mh,   // (L,M,2,6,6)
    const float* __restrict__ Mv,   // (L,M,2,6,6)
    const float* __restrict__ Vp,   // (L,M,2,6)
    const float* __restrict__ Tp,   // (L,M,2,6,6,6)
    const float* __restrict__ Wp,   // (L,M,6)
    const float* __restrict__ Cp,   // (L,M)
    const float* __restrict__ Ep,   // (L,M,6)
    const int*   __restrict__ X,    // (B,64)
    float*       __restrict__ out,
    int Bn, int writeImag)
{
    // merged fp16 rows: [site][row(=a*6+o)][24 uints]: 18 T | 3 mh(+diag) | 3 mv(+diag)
    __shared__ unsigned Tl[16 * 12 * 24];    // 18432 B
    __shared__ uint4    VEh[16 * 4];         // 1024 B {vv01, vv2|e0, e1|e2, pad} fp16

    const int t   = threadIdx.x;
    const int sub = t & 3;
    int b = blockIdx.x * SPB + (t >> 2);
    const bool valid = (b < Bn);
    if (!valid) b = Bn - 1;          // clamp loads; no early return (barriers!)

    // cooperative bit pack (each lane 16 qubits, OR-combine across group)
    unsigned long long bits;
    {
        const int4* xr = reinterpret_cast<const int4*>(X + (size_t)b * NQ + sub * 16);
        unsigned long long part = 0ull;
        #pragma unroll
        for (int q = 0; q < 4; ++q) {
            int4 v = xr[q];
            part |= (unsigned long long)(v.x & 1) << (4 * q + 0);
            part |= (unsigned long long)(v.y & 1) << (4 * q + 1);
            part |= (unsigned long long)(v.z & 1) << (4 * q + 2);
            part |= (unsigned long long)(v.w & 1) << (4 * q + 3);
        }
        bits = part << (16 * sub);
        bits |= __shfl_xor(bits, 1, 64);
        bits |= __shfl_xor(bits, 2, 64);
    }

    const int mya = sub >> 1;

    // vertical state in registers: packed fp16, replicated in all 4 lanes
    unsigned vsr0[8], vsr1[8], vsr2[8];
    #pragma unroll
    for (int j = 0; j < 8; ++j) { vsr0[j] = 0u; vsr1[j] = 0u; vsr2[j] = 0u; }

    float hh[6];
    h2v hhp0, hhp1, hhp2;
    float amp2 = 1.f, phi = 0.f;

    for (int ch = 0; ch < 4; ++ch) {
        __syncthreads();             // previous chunk fully consumed
        // ---- stage chunk ch (sites 16ch..16ch+15)
        {
            // T: 216 fp32-pairs/site -> h2, row = pair/18, w = pair%18
            const float2* gT = reinterpret_cast<const float2*>(Tp + ch * 6912);
            for (int p = t; p < 3456; p += BT) {
                int site = p / 216, rr = p - site * 216;
                int row = rr / 18,  w  = rr - row * 18;
                float2 v = gT[p];
                H2U hu; hu.hh = __floats2half2_rn(v.x, v.y);
                Tl[(site * 12 + row) * 24 + w] = hu.u;
            }
            // Mh/Mv with residual diag fold (+1.0 at c == o_r)
            const float2* gH = reinterpret_cast<const float2*>(Mh + ch * 1152);
            const float2* gV = reinterpret_cast<const float2*>(Mv + ch * 1152);
            for (int p = t; p < 576; p += BT) {
                int site = p / 36, rr = p - site * 36;
                int row = rr / 3,  w  = rr - row * 3;
                int o_r = row - ((row >= 6) ? 6 : 0);     // row % 6
                float2 vh = gH[p], vv2 = gV[p];
                if ((o_r >> 1) == w) {
                    if (o_r & 1) { vh.y += 1.f; vv2.y += 1.f; }
                    else         { vh.x += 1.f; vv2.x += 1.f; }
                }
                H2U a; a.hh = __floats2half2_rn(vh.x, vh.y);
                H2U c; c.hh = __floats2half2_rn(vv2.x, vv2.y);
                Tl[(site * 12 + row) * 24 + 18 + w] = a.u;
                Tl[(site * 12 + row) * 24 + 21 + w] = c.u;
            }
            // VE packed fp16: one uint4 per (site, sub)
            if (t < 64) {
                int site = t >> 2, sb = t & 3;
                const float* vp = Vp + ch * 192 + site * 12 + sb * 3;
                const float* ep = Ep + ch * 96 + site * 6 + (sb & 1) * 3;
                float e0 = ep[0], e1 = ep[1], e2v = ep[2];
                H2U u0, u1, u2;
                u0.hh = __floats2half2_rn(vp[0], vp[1]);
                u1.hh = __floats2half2_rn(vp[2], e0 * e0);
                u2.hh = __floats2half2_rn(e1 * e1, e2v * e2v);
                VEh[site * 4 + sb] = make_uint4(u0.u, u1.u, u2.u, 0u);
            }
        }
        __syncthreads();             // chunk visible

        #pragma unroll
        for (int ih = 0; ih < 2; ++ih) {
            const unsigned cbr = (unsigned)(bits >> (ch * 16 + ih * 8)) & 0xFFu;

            #pragma unroll
            for (int qq = 0; qq < 8; ++qq) {
                const int j    = ih ? 7 - qq : qq;      // snake column (static)
                const int slot = ih * 8 + j;
                const int siteg = ch * 16 + slot;

                const unsigned* Tb = Tl + (slot * 12 + sub * 3) * 24;
                const float* wq = Wp + siteg * 6;       // uniform -> scalar path
                const float  ck = Cp[siteg];            // uniform -> scalar path

                if (qq == 0) {                          // left boundary
                    #pragma unroll
                    for (int o = 0; o < 6; ++o) hh[o] = 1.f;
                    H2U one; one.u = 0x3C003C00u;
                    hhp0 = one.h; hhp1 = one.h; hhp2 = one.h;
                }

                // vertical state from registers (static index j)
                const h2v hvh0 = u2h(vsr0[j]);
                const h2v hvh1 = u2h(vsr1[j]);
                const h2v hvh2 = u2h(vsr2[j]);

                // VE: one b128, unpack via cvt
                uint4 ve = VEh[slot * 4 + sub];
                H2U e0u, e1u, e2u;
                e0u.u = ve.x; e1u.u = ve.y; e2u.u = ve.z;
                const float vv_[3] = { __low2float(e0u.hh), __high2float(e0u.hh),
                                       __low2float(e1u.hh) };
                const float e2_[3] = { __high2float(e1u.hh), __low2float(e2u.hh),
                                       __high2float(e2u.hh) };

                float acc[3];
                #pragma unroll
                for (int lr = 0; lr < 3; ++lr) {
                    const unsigned* Tr = Tb + lr * 24;
                    uint4 tA = *reinterpret_cast<const uint4*>(Tr);      // T 0..3
                    uint4 tB = *reinterpret_cast<const uint4*>(Tr + 4);  // T 4..7
                    uint4 tC = *reinterpret_cast<const uint4*>(Tr + 8);  // T 8..11
                    uint4 tD = *reinterpret_cast<const uint4*>(Tr + 12); // T 12..15
                    uint4 tE = *reinterpret_cast<const uint4*>(Tr + 16); // T16 T17 mh0 mh1
                    uint4 tF = *reinterpret_cast<const uint4*>(Tr + 20); // mh2 mv0 mv1 mv2
                    const unsigned tw[18] = {tA.x,tA.y,tA.z,tA.w, tB.x,tB.y,tB.z,tB.w,
                                             tC.x,tC.y,tC.z,tC.w, tD.x,tD.y,tD.z,tD.w,
                                             tE.x,tE.y};
                    float sc[6];
                    #pragma unroll
                    for (int c = 0; c < 6; ++c)
                        sc[c] = fdot2u(tw[c*3+0], hvh0,
                                fdot2u(tw[c*3+1], hvh1,
                                fdot2u(tw[c*3+2], hvh2, 0.f)));

                    float ta = fmaf(sc[0], hh[0], fmaf(sc[2], hh[2], sc[4]*hh[4]));
                    float tb = fmaf(sc[1], hh[1], fmaf(sc[3], hh[3], sc[5]*hh[5]));
                    float md = fdot2u(tE.z, hhp0, fdot2u(tE.w, hhp1,
                               fdot2u(tF.x, hhp2, vv_[lr])));   // diag-folded + V seed
                    float nd = fdot2u(tF.y, hvh0, fdot2u(tF.z, hvh1,
                               fdot2u(tF.w, hvh2, 0.f)));       // diag-folded
                    acc[lr] = (ta + tb) + (md + nd);
                }

                // 4-lane reductions via DPP quad_perm (pure VALU, no LDS)
                float q0_ = acc[0]*acc[0], q1_ = acc[1]*acc[1], q2_ = acc[2]*acc[2];
                float ssl = (q0_ + q1_) + q2_;
                float pq  = fmaf(e2_[0], q0_, fmaf(e2_[1], q1_, e2_[2] * q2_));
                float s1  = ssl + DPPF(ssl, QP_XOR1);
                float ssq = s1 + DPPF(s1, QP_XOR2);
                float p1  = pq + DPPF(pq, QP_XOR1);
                float px  = DPPF(p1, QP_XOR2);
                const float inv = FAST_RSQ(ssq + 1e-12f);

                const int sel = (cbr >> qq) & 1;
                const float qsel = (mya == sel) ? p1 : px;
                amp2 *= qsel * FAST_RCP(p1 + px);

                // normalize, XOR2-swap pre-select, then 6 quad-broadcasts
                float an0 = acc[0] * inv, an1 = acc[1] * inv, an2 = acc[2] * inv;
                float sw0 = DPPF(an0, QP_XOR2);
                float sw1 = DPPF(an1, QP_XOR2);
                float sw2 = DPPF(an2, QP_XOR2);
                an0 = sel ? sw0 : an0;
                an1 = sel ? sw1 : an1;
                an2 = sel ? sw2 : an2;
                hh[0] = DPPF(an0, QP_BC0); hh[3] = DPPF(an0, QP_BC1);
                hh[1] = DPPF(an1, QP_BC0); hh[4] = DPPF(an1, QP_BC1);
                hh[2] = DPPF(an2, QP_BC0); hh[5] = DPPF(an2, QP_BC1);
                hhp0 = pack2(hh[0], hh[1]);
                hhp1 = pack2(hh[2], hh[3]);
                hhp2 = pack2(hh[4], hh[5]);

                // phase (scalar-operand FMA tree)
                float pA = fmaf(wq[1], hh[1], wq[0] * hh[0]);
                float pB = fmaf(wq[3], hh[3], wq[2] * hh[2]);
                float pC = fmaf(wq[5], hh[5], fmaf(wq[4], hh[4], ck));
                phi += (pA + pB) + pC;

                // vertical state update (registers, all lanes, static index)
                vsr0[j] = h2u(hhp0);
                vsr1[j] = h2u(hhp1);
                vsr2[j] = h2u(hhp2);
            }
        }
    }

    if (sub == 0 && valid) {
        const float amp = sqrtf(amp2);
        if (writeImag) {
            out[2 * b + 0] = amp * cosf(phi);
            out[2 * b + 1] = amp * sinf(phi);
        } else {
            out[b] = amp * cosf(phi);
        }
    }
}

extern "C" void kernel_launch(void* const* d_in, const int* in_sizes, int n_in,
                              void* d_out, int out_size, void* d_ws, size_t ws_size,
                              hipStream_t stream) {
    const float* Mh = (const float*)d_in[0];
    const float* Mv = (const float*)d_in[1];
    const float* Vp = (const float*)d_in[2];
    const float* Tp = (const float*)d_in[3];
    const float* Wp = (const float*)d_in[4];
    const float* Cp = (const float*)d_in[5];
    const float* Ep = (const float*)d_in[6];
    const int*   X  = (const int*)d_in[7];
    float* out = (float*)d_out;

    const int Bn = in_sizes[7] / NQ;                 // 32768
    const int writeImag = (out_size >= 2 * Bn) ? 1 : 0;
    const int grid = (Bn + SPB - 1) / SPB;           // 512 blocks of 256 threads

    mps_rnn18<<<grid, BT, 0, stream>>>(Mh, Mv, Vp, Tp, Wp, Cp, Ep, X, out,
                                       Bn, writeImag);
}

// Round 19
// 66.382 us; speedup vs baseline: 1.3873x; 1.3873x over previous
//
#include <hip/hip_runtime.h>
#include <hip/hip_fp16.h>
#include <math.h>

// MPS-RNN 2D forward: L=8, M=8, DCUT=6, HL=2, N=64, B=32768
// Round-19 = round-16 structure (65.0us, vs-state in LDS, 44 VGPR) + the two
// register-free LDS cuts from r17:
//   (a) V+eta^2 packed fp16 -> one b128 read (+6 cvt)
//   (b) W/C via wave-uniform scalar (s_load) path -> Wl LDS read deleted
// r17/r18 lesson: register vertical state needs ~150 VGPR -> spill (capped)
// or halved occupancy (uncapped). Keep VGPR well under 128.

#define NQ  64
#define BT  256
#define SPB 64

typedef _Float16 h2v __attribute__((ext_vector_type(2)));
typedef __fp16  p2v __attribute__((ext_vector_type(2)));
union H2U { unsigned u; h2v h; __half2 hh; };

static __device__ __forceinline__ h2v pack2(float a, float b) {
    p2v p = __builtin_amdgcn_cvt_pkrtz(a, b);
    h2v r; __builtin_memcpy(&r, &p, sizeof(r));
    return r;
}
static __device__ __forceinline__ h2v u2h(unsigned u) {
    h2v r; __builtin_memcpy(&r, &u, sizeof(r));
    return r;
}
static __device__ __forceinline__ unsigned h2u(h2v h) {
    unsigned r; __builtin_memcpy(&r, &h, sizeof(r));
    return r;
}

#define DPPF(x, ctrl) __int_as_float(__builtin_amdgcn_update_dpp(            \
    __float_as_int(x), __float_as_int(x), (ctrl), 0xF, 0xF, false))
#define QP_XOR1 0xB1   // quad_perm [1,0,3,2]
#define QP_XOR2 0x4E   // quad_perm [2,3,0,1]
#define QP_BC0  0x00
#define QP_BC1  0x55

#if defined(__has_builtin)
#  if __has_builtin(__builtin_amdgcn_rcpf)
#    define FAST_RCP(x) __builtin_amdgcn_rcpf(x)
#  else
#    define FAST_RCP(x) (1.0f / (x))
#  endif
#  if __has_builtin(__builtin_amdgcn_rsqf)
#    define FAST_RSQ(x) __builtin_amdgcn_rsqf(x)
#  else
#    define FAST_RSQ(x) rsqrtf(x)
#  endif
#  if __has_builtin(__builtin_amdgcn_fdot2)
#    define HAS_FDOT2 1
#  endif
#else
#  define FAST_RCP(x) (1.0f / (x))
#  define FAST_RSQ(x) rsqrtf(x)
#endif

static __device__ __forceinline__ float fdot2u(unsigned a, h2v b, float c) {
#ifdef HAS_FDOT2
    H2U u; u.u = a;
    return __builtin_amdgcn_fdot2(u.h, b, c, false);
#else
    H2U u; u.u = a;
    return fmaf((float)u.h.x, (float)b.x, fmaf((float)u.h.y, (float)b.y, c));
#endif
}

__global__ __launch_bounds__(BT, 1) void mps_rnn19(
    const float* __restrict__ Mh,   // (L,M,2,6,6)
    const float* __restrict__ Mv,   // (L,M,2,6,6)
    const float* __restrict__ Vp,   // (L,M,2,6)
    const float* __restrict__ Tp,   // (L,M,2,6,6,6)
    const float* __restrict__ Wp,   // (L,M,6)
    const float* __restrict__ Cp,   // (L,M)
    const float* __restrict__ Ep,   // (L,M,6)
    const int*   __restrict__ X,    // (B,64)
    float*       __restrict__ out,
    int Bn, int writeImag)
{
    // merged fp16 rows: [site][row(=a*6+o)][24 uints]: 18 T | 3 mh(+diag) | 3 mv(+diag)
    __shared__ unsigned Tl[16 * 12 * 24];    // 18432 B
    __shared__ uint4    VEh[16 * 4];         // 1024 B {vv01, vv2|e0, e1|e2, pad} fp16
    __shared__ unsigned vsm[8 * 64 * 4];     // 8192 B vertical state [j][s][4] packed fp16

    const int t   = threadIdx.x;
    const int sub = t & 3;
    const int s   = t >> 2;
    int b = blockIdx.x * SPB + s;
    const bool valid = (b < Bn);
    if (!valid) b = Bn - 1;          // clamp loads; no early return (barriers!)

    // cooperative bit pack (each lane 16 qubits, OR-combine across group)
    unsigned long long bits;
    {
        const int4* xr = reinterpret_cast<const int4*>(X + (size_t)b * NQ + sub * 16);
        unsigned long long part = 0ull;
        #pragma unroll
        for (int q = 0; q < 4; ++q) {
            int4 v = xr[q];
            part |= (unsigned long long)(v.x & 1) << (4 * q + 0);
            part |= (unsigned long long)(v.y & 1) << (4 * q + 1);
            part |= (unsigned long long)(v.z & 1) << (4 * q + 2);
            part |= (unsigned long long)(v.w & 1) << (4 * q + 3);
        }
        bits = part << (16 * sub);
        bits |= __shfl_xor(bits, 1, 64);
        bits |= __shfl_xor(bits, 2, 64);
    }

    for (int u = t; u < 8 * 64 * 4; u += BT) vsm[u] = 0u;

    const int mya = sub >> 1;

    float hh[6];
    h2v hhp0, hhp1, hhp2;
    float amp2 = 1.f, phi = 0.f;

    for (int ch = 0; ch < 4; ++ch) {
        __syncthreads();             // previous chunk fully consumed
        // ---- stage chunk ch (sites 16ch..16ch+15)
        {
            // T: 216 fp32-pairs/site -> h2, row = pair/18, w = pair%18
            const float2* gT = reinterpret_cast<const float2*>(Tp + ch * 6912);
            for (int p = t; p < 3456; p += BT) {
                int site = p / 216, rr = p - site * 216;
                int row = rr / 18,  w  = rr - row * 18;
                float2 v = gT[p];
                H2U hu; hu.hh = __floats2half2_rn(v.x, v.y);
                Tl[(site * 12 + row) * 24 + w] = hu.u;
            }
            // Mh/Mv with residual diag fold (+1.0 at c == o_r)
            const float2* gH = reinterpret_cast<const float2*>(Mh + ch * 1152);
            const float2* gV = reinterpret_cast<const float2*>(Mv + ch * 1152);
            for (int p = t; p < 576; p += BT) {
                int site = p / 36, rr = p - site * 36;
                int row = rr / 3,  w  = rr - row * 3;
                int o_r = row - ((row >= 6) ? 6 : 0);     // row % 6
                float2 vh = gH[p], vv2 = gV[p];
                if ((o_r >> 1) == w) {
                    if (o_r & 1) { vh.y += 1.f; vv2.y += 1.f; }
                    else         { vh.x += 1.f; vv2.x += 1.f; }
                }
                H2U a; a.hh = __floats2half2_rn(vh.x, vh.y);
                H2U c; c.hh = __floats2half2_rn(vv2.x, vv2.y);
                Tl[(site * 12 + row) * 24 + 18 + w] = a.u;
                Tl[(site * 12 + row) * 24 + 21 + w] = c.u;
            }
            // VE packed fp16: one uint4 per (site, sub)
            if (t < 64) {
                int site = t >> 2, sb = t & 3;
                const float* vp = Vp + ch * 192 + site * 12 + sb * 3;
                const float* ep = Ep + ch * 96 + site * 6 + (sb & 1) * 3;
                float e0 = ep[0], e1 = ep[1], e2v = ep[2];
                H2U u0, u1, u2;
                u0.hh = __floats2half2_rn(vp[0], vp[1]);
                u1.hh = __floats2half2_rn(vp[2], e0 * e0);
                u2.hh = __floats2half2_rn(e1 * e1, e2v * e2v);
                VEh[site * 4 + sb] = make_uint4(u0.u, u1.u, u2.u, 0u);
            }
        }
        __syncthreads();             // chunk visible

        #pragma unroll
        for (int ih = 0; ih < 2; ++ih) {
            const unsigned cbr = (unsigned)(bits >> (ch * 16 + ih * 8)) & 0xFFu;

            #pragma unroll 2
            for (int qq = 0; qq < 8; ++qq) {
                const int j    = ih ? 7 - qq : qq;      // snake column
                const int slot = ih * 8 + j;
                const int siteg = ch * 16 + slot;

                const unsigned* Tb = Tl + (slot * 12 + sub * 3) * 24;
                const float* wq = Wp + siteg * 6;       // uniform -> scalar path
                const float  ck = Cp[siteg];            // uniform -> scalar path

                if (qq == 0) {                          // left boundary
                    #pragma unroll
                    for (int o = 0; o < 6; ++o) hh[o] = 1.f;
                    H2U one; one.u = 0x3C003C00u;
                    hhp0 = one.h; hhp1 = one.h; hhp2 = one.h;
                }

                // vertical state: packed fp16, one b128 read
                uint4 hvu = *reinterpret_cast<const uint4*>(vsm + j * 256 + s * 4);
                const h2v hvh0 = u2h(hvu.x);
                const h2v hvh1 = u2h(hvu.y);
                const h2v hvh2 = u2h(hvu.z);

                // VE: one b128, unpack via cvt
                uint4 ve = VEh[slot * 4 + sub];
                H2U e0u, e1u, e2u;
                e0u.u = ve.x; e1u.u = ve.y; e2u.u = ve.z;
                const float vv_[3] = { __low2float(e0u.hh), __high2float(e0u.hh),
                                       __low2float(e1u.hh) };
                const float e2_[3] = { __high2float(e1u.hh), __low2float(e2u.hh),
                                       __high2float(e2u.hh) };

                float acc[3];
                #pragma unroll
                for (int lr = 0; lr < 3; ++lr) {
                    const unsigned* Tr = Tb + lr * 24;
                    uint4 tA = *reinterpret_cast<const uint4*>(Tr);      // T 0..3
                    uint4 tB = *reinterpret_cast<const uint4*>(Tr + 4);  // T 4..7
                    uint4 tC = *reinterpret_cast<const uint4*>(Tr + 8);  // T 8..11
                    uint4 tD = *reinterpret_cast<const uint4*>(Tr + 12); // T 12..15
                    uint4 tE = *reinterpret_cast<const uint4*>(Tr + 16); // T16 T17 mh0 mh1
                    uint4 tF = *reinterpret_cast<const uint4*>(Tr + 20); // mh2 mv0 mv1 mv2
                    const unsigned tw[18] = {tA.x,tA.y,tA.z,tA.w, tB.x,tB.y,tB.z,tB.w,
                                             tC.x,tC.y,tC.z,tC.w, tD.x,tD.y,tD.z,tD.w,
                                             tE.x,tE.y};
                    float sc[6];
                    #pragma unroll
                    for (int c = 0; c < 6; ++c)
                        sc[c] = fdot2u(tw[c*3+0], hvh0,
                                fdot2u(tw[c*3+1], hvh1,
                                fdot2u(tw[c*3+2], hvh2, 0.f)));

                    float ta = fmaf(sc[0], hh[0], fmaf(sc[2], hh[2], sc[4]*hh[4]));
                    float tb = fmaf(sc[1], hh[1], fmaf(sc[3], hh[3], sc[5]*hh[5]));
                    float md = fdot2u(tE.z, hhp0, fdot2u(tE.w, hhp1,
                               fdot2u(tF.x, hhp2, vv_[lr])));   // diag-folded + V seed
                    float nd = fdot2u(tF.y, hvh0, fdot2u(tF.z, hvh1,
                               fdot2u(tF.w, hvh2, 0.f)));       // diag-folded
                    acc[lr] = (ta + tb) + (md + nd);
                }

                // 4-lane reductions via DPP quad_perm (pure VALU, no LDS)
                float q0_ = acc[0]*acc[0], q1_ = acc[1]*acc[1], q2_ = acc[2]*acc[2];
                float ssl = (q0_ + q1_) + q2_;
                float pq  = fmaf(e2_[0], q0_, fmaf(e2_[1], q1_, e2_[2] * q2_));
                float s1  = ssl + DPPF(ssl, QP_XOR1);
                float ssq = s1 + DPPF(s1, QP_XOR2);
                float p1  = pq + DPPF(pq, QP_XOR1);
                float px  = DPPF(p1, QP_XOR2);
                const float inv = FAST_RSQ(ssq + 1e-12f);

                const int sel = (cbr >> qq) & 1;
                const float qsel = (mya == sel) ? p1 : px;
                amp2 *= qsel * FAST_RCP(p1 + px);

                // normalize, XOR2-swap pre-select, then 6 quad-broadcasts
                float an0 = acc[0] * inv, an1 = acc[1] * inv, an2 = acc[2] * inv;
                float sw0 = DPPF(an0, QP_XOR2);
                float sw1 = DPPF(an1, QP_XOR2);
                float sw2 = DPPF(an2, QP_XOR2);
                an0 = sel ? sw0 : an0;
                an1 = sel ? sw1 : an1;
                an2 = sel ? sw2 : an2;
                hh[0] = DPPF(an0, QP_BC0); hh[3] = DPPF(an0, QP_BC1);
                hh[1] = DPPF(an1, QP_BC0); hh[4] = DPPF(an1, QP_BC1);
                hh[2] = DPPF(an2, QP_BC0); hh[5] = DPPF(an2, QP_BC1);
                hhp0 = pack2(hh[0], hh[1]);
                hhp1 = pack2(hh[2], hh[3]);
                hhp2 = pack2(hh[4], hh[5]);

                // phase (scalar-operand FMA tree)
                float pA = fmaf(wq[1], hh[1], wq[0] * hh[0]);
                float pB = fmaf(wq[3], hh[3], wq[2] * hh[2]);
                float pC = fmaf(wq[5], hh[5], fmaf(wq[4], hh[4], ck));
                phi += (pA + pB) + pC;

                if (sub == 0) {
                    *reinterpret_cast<uint4*>(vsm + j * 256 + s * 4) =
                        make_uint4(h2u(hhp0), h2u(hhp1), h2u(hhp2), 0u);
                }
            }
        }
    }

    if (sub == 0 && valid) {
        const float amp = sqrtf(amp2);
        if (writeImag) {
            out[2 * b + 0] = amp * cosf(phi);
            out[2 * b + 1] = amp * sinf(phi);
        } else {
            out[b] = amp * cosf(phi);
        }
    }
}

extern "C" void kernel_launch(void* const* d_in, const int* in_sizes, int n_in,
                              void* d_out, int out_size, void* d_ws, size_t ws_size,
                              hipStream_t stream) {
    const float* Mh = (const float*)d_in[0];
    const float* Mv = (const float*)d_in[1];
    const float* Vp = (const float*)d_in[2];
    const float* Tp = (const float*)d_in[3];
    const float* Wp = (const float*)d_in[4];
    const float* Cp = (const float*)d_in[5];
    const float* Ep = (const float*)d_in[6];
    const int*   X  = (const int*)d_in[7];
    float* out = (float*)d_out;

    const int Bn = in_sizes[7] / NQ;                 // 32768
    const int writeImag = (out_size >= 2 * Bn) ? 1 : 0;
    const int grid = (Bn + SPB - 1) / SPB;           // 512 blocks of 256 threads

    mps_rnn19<<<grid, BT, 0, stream>>>(Mh, Mv, Vp, Tp, Wp, Cp, Ep, X, out,
                                       Bn, writeImag);
}

// Round 20
// 63.329 us; speedup vs baseline: 1.4542x; 1.0482x over previous
//
#include <hip/hip_runtime.h>
#include <hip/hip_fp16.h>
#include <math.h>

// MPS-RNN 2D forward: L=8, M=8, DCUT=6, HL=2, N=64, B=32768
// Round-20 = round-16 base (65.0us, VALU-bound per r19 evidence) + two cuts:
//  (1) one-time repack kernel -> d_ws: staging arithmetic (idx math, fp16 cvt,
//      diag fold, eta^2, W/C pack) amortized out of the 512-block main kernel;
//      main staging = pure uint4 copy.
//  (2) snake row-boundary bypass: at qq==0 reuse carried hhp (the column just
//      written) instead of the LDS round-trip; skip the dead qq==7 vs write.
// Fallback to exact r16 kernel if ws_size < 83KB.

#define NQ  64
#define BT  256
#define SPB 64
#define CHUNK_U 5184   // uints per chunk image: 4608 T/M | 512 VE(f32) | 64 Wl

typedef _Float16 h2v __attribute__((ext_vector_type(2)));
typedef __fp16  p2v __attribute__((ext_vector_type(2)));
union H2U { unsigned u; h2v h; __half2 hh; };

static __device__ __forceinline__ h2v pack2(float a, float b) {
    p2v p = __builtin_amdgcn_cvt_pkrtz(a, b);
    h2v r; __builtin_memcpy(&r, &p, sizeof(r));
    return r;
}
static __device__ __forceinline__ h2v u2h(unsigned u) {
    h2v r; __builtin_memcpy(&r, &u, sizeof(r));
    return r;
}
static __device__ __forceinline__ unsigned h2u(h2v h) {
    unsigned r; __builtin_memcpy(&r, &h, sizeof(r));
    return r;
}

#define DPPF(x, ctrl) __int_as_float(__builtin_amdgcn_update_dpp(            \
    __float_as_int(x), __float_as_int(x), (ctrl), 0xF, 0xF, false))
#define QP_XOR1 0xB1
#define QP_XOR2 0x4E
#define QP_BC0  0x00
#define QP_BC1  0x55

#if defined(__has_builtin)
#  if __has_builtin(__builtin_amdgcn_rcpf)
#    define FAST_RCP(x) __builtin_amdgcn_rcpf(x)
#  else
#    define FAST_RCP(x) (1.0f / (x))
#  endif
#  if __has_builtin(__builtin_amdgcn_rsqf)
#    define FAST_RSQ(x) __builtin_amdgcn_rsqf(x)
#  else
#    define FAST_RSQ(x) rsqrtf(x)
#  endif
#  if __has_builtin(__builtin_amdgcn_fdot2)
#    define HAS_FDOT2 1
#  endif
#else
#  define FAST_RCP(x) (1.0f / (x))
#  define FAST_RSQ(x) rsqrtf(x)
#endif

static __device__ __forceinline__ float fdot2u(unsigned a, h2v b, float c) {
#ifdef HAS_FDOT2
    H2U u; u.u = a;
    return __builtin_amdgcn_fdot2(u.h, b, c, false);
#else
    H2U u; u.u = a;
    return fmaf((float)u.h.x, (float)b.x, fmaf((float)u.h.y, (float)b.y, c));
#endif
}

// ---------- one-time param repack (grid 4 = one block per 16-site chunk) ----
__global__ void repack_k(
    const float* __restrict__ Mh, const float* __restrict__ Mv,
    const float* __restrict__ Vp, const float* __restrict__ Tp,
    const float* __restrict__ Wp, const float* __restrict__ Cp,
    const float* __restrict__ Ep, unsigned* __restrict__ ws)
{
    const int ch = blockIdx.x;
    const int t  = threadIdx.x;
    unsigned* Tm = ws + ch * CHUNK_U;
    float*    VE = reinterpret_cast<float*>(Tm + 4608);
    uint4*    Wl = reinterpret_cast<uint4*>(Tm + 4608 + 512);

    const float2* gT = reinterpret_cast<const float2*>(Tp + ch * 6912);
    for (int p = t; p < 3456; p += BT) {
        int site = p / 216, rr = p - site * 216;
        int row = rr / 18,  w  = rr - row * 18;
        float2 v = gT[p];
        H2U hu; hu.hh = __floats2half2_rn(v.x, v.y);
        Tm[(site * 12 + row) * 24 + w] = hu.u;
    }
    const float2* gH = reinterpret_cast<const float2*>(Mh + ch * 1152);
    const float2* gV = reinterpret_cast<const float2*>(Mv + ch * 1152);
    for (int p = t; p < 576; p += BT) {
        int site = p / 36, rr = p - site * 36;
        int row = rr / 3,  w  = rr - row * 3;
        int o_r = row - ((row >= 6) ? 6 : 0);     // row % 6
        float2 vh = gH[p], vv2 = gV[p];
        if ((o_r >> 1) == w) {                    // residual diag fold (+1)
            if (o_r & 1) { vh.y += 1.f; vv2.y += 1.f; }
            else         { vh.x += 1.f; vv2.x += 1.f; }
        }
        H2U a; a.hh = __floats2half2_rn(vh.x, vh.y);
        H2U c; c.hh = __floats2half2_rn(vv2.x, vv2.y);
        Tm[(site * 12 + row) * 24 + 18 + w] = a.u;
        Tm[(site * 12 + row) * 24 + 21 + w] = c.u;
    }
    if (t < 192) {
        int site = t / 12, q = t - site * 12;
        int sb = q / 3,    c = q - sb * 3;
        VE[(site * 4 + sb) * 8 + c] = Vp[ch * 192 + t];
        float e = Ep[ch * 96 + site * 6 + (sb & 1) * 3 + c];
        VE[(site * 4 + sb) * 8 + 3 + c] = e * e;
    } else if (t < 208) {
        int site = t - 192;
        const float2* gw = reinterpret_cast<const float2*>(Wp) + ch * 48 + site * 3;
        float2 w01 = gw[0], w23 = gw[1], w45 = gw[2];
        H2U u0, u1, u2;
        u0.hh = __floats2half2_rn(w01.x, w01.y);
        u1.hh = __floats2half2_rn(w23.x, w23.y);
        u2.hh = __floats2half2_rn(w45.x, w45.y);
        Wl[site] = make_uint4(u0.u, u1.u, u2.u,
                              __float_as_uint(Cp[ch * 16 + site]));
    }
}

// ---------- main kernel (ws-staged) -----------------------------------------
__global__ __launch_bounds__(BT, 1) void mps_rnn20(
    const unsigned* __restrict__ ws,
    const int* __restrict__ X,
    float* __restrict__ out, int Bn, int writeImag)
{
    __shared__ uint4    ldsb[CHUNK_U / 4];   // 20736 B chunk image
    __shared__ unsigned vsm[8 * 64 * 4];     // 8192 B vertical state (packed fp16)

    unsigned*     Tl = reinterpret_cast<unsigned*>(ldsb);
    const float*  VE = reinterpret_cast<const float*>(Tl + 4608);
    const uint4*  Wl = reinterpret_cast<const uint4*>(Tl + 4608 + 512);

    const int t   = threadIdx.x;
    const int sub = t & 3;
    const int s   = t >> 2;
    int b = blockIdx.x * SPB + s;
    const bool valid = (b < Bn);
    if (!valid) b = Bn - 1;          // clamp loads; no early return (barriers!)

    unsigned long long bits;
    {
        const int4* xr = reinterpret_cast<const int4*>(X + (size_t)b * NQ + sub * 16);
        unsigned long long part = 0ull;
        #pragma unroll
        for (int q = 0; q < 4; ++q) {
            int4 v = xr[q];
            part |= (unsigned long long)(v.x & 1) << (4 * q + 0);
            part |= (unsigned long long)(v.y & 1) << (4 * q + 1);
            part |= (unsigned long long)(v.z & 1) << (4 * q + 2);
            part |= (unsigned long long)(v.w & 1) << (4 * q + 3);
        }
        bits = part << (16 * sub);
        bits |= __shfl_xor(bits, 1, 64);
        bits |= __shfl_xor(bits, 2, 64);
    }

    for (int u = t; u < 8 * 64 * 4; u += BT) vsm[u] = 0u;

    const int mya = sub >> 1;

    float hh[6];
    h2v hhp0, hhp1, hhp2;
    float amp2 = 1.f, phi = 0.f;

    for (int ch = 0; ch < 4; ++ch) {
        __syncthreads();             // previous chunk fully consumed
        // pure-copy staging (no arithmetic; image prebuilt by repack_k)
        {
            const uint4* g4 = reinterpret_cast<const uint4*>(ws + ch * CHUNK_U);
            #pragma unroll
            for (int i = 0; i < 6; ++i) {
                int idx = t + i * BT;
                if (idx < CHUNK_U / 4) ldsb[idx] = g4[idx];
            }
        }
        __syncthreads();             // chunk visible

        #pragma unroll
        for (int ih = 0; ih < 2; ++ih) {
            const unsigned cbr = (unsigned)(bits >> (ch * 16 + ih * 8)) & 0xFFu;

            #pragma unroll 2
            for (int qq = 0; qq < 8; ++qq) {
                const int j    = ih ? 7 - qq : qq;      // snake column
                const int slot = ih * 8 + j;

                const unsigned* Tb = Tl + (slot * 12 + sub * 3) * 24;
                const float*   VEb = VE + (slot * 4 + sub) * 8;

                h2v hvh0, hvh1, hvh2;
                if (qq == 0) {
                    // row-boundary bypass: this column was written last step
                    // of the previous row; its value is the carried hhp.
                    if (ch == 0 && ih == 0) {
                        H2U z; z.u = 0u;
                        hvh0 = z.h; hvh1 = z.h; hvh2 = z.h;   // bottom boundary
                    } else {
                        hvh0 = hhp0; hvh1 = hhp1; hvh2 = hhp2;
                    }
                    #pragma unroll
                    for (int o = 0; o < 6; ++o) hh[o] = 1.f;  // left boundary
                    H2U one; one.u = 0x3C003C00u;
                    hhp0 = one.h; hhp1 = one.h; hhp2 = one.h;
                } else {
                    uint4 hvu = *reinterpret_cast<const uint4*>(vsm + j * 256 + s * 4);
                    hvh0 = u2h(hvu.x); hvh1 = u2h(hvu.y); hvh2 = u2h(hvu.z);
                }

                float4 ve0 = *reinterpret_cast<const float4*>(VEb);     // v0 v1 v2 e0^2
                float2 ve1 = *reinterpret_cast<const float2*>(VEb + 4); // e1^2 e2^2
                const float vv_[3] = { ve0.x, ve0.y, ve0.z };
                const float e2_[3] = { ve0.w, ve1.x, ve1.y };

                float acc[3];
                #pragma unroll
                for (int lr = 0; lr < 3; ++lr) {
                    const unsigned* Tr = Tb + lr * 24;
                    uint4 tA = *reinterpret_cast<const uint4*>(Tr);      // T 0..3
                    uint4 tB = *reinterpret_cast<const uint4*>(Tr + 4);  // T 4..7
                    uint4 tC = *reinterpret_cast<const uint4*>(Tr + 8);  // T 8..11
                    uint4 tD = *reinterpret_cast<const uint4*>(Tr + 12); // T 12..15
                    uint4 tE = *reinterpret_cast<const uint4*>(Tr + 16); // T16 T17 mh0 mh1
                    uint4 tF = *reinterpret_cast<const uint4*>(Tr + 20); // mh2 mv0 mv1 mv2
                    const unsigned tw[18] = {tA.x,tA.y,tA.z,tA.w, tB.x,tB.y,tB.z,tB.w,
                                             tC.x,tC.y,tC.z,tC.w, tD.x,tD.y,tD.z,tD.w,
                                             tE.x,tE.y};
                    float sc[6];
                    #pragma unroll
                    for (int c = 0; c < 6; ++c)
                        sc[c] = fdot2u(tw[c*3+0], hvh0,
                                fdot2u(tw[c*3+1], hvh1,
                                fdot2u(tw[c*3+2], hvh2, 0.f)));

                    float ta = fmaf(sc[0], hh[0], fmaf(sc[2], hh[2], sc[4]*hh[4]));
                    float tb = fmaf(sc[1], hh[1], fmaf(sc[3], hh[3], sc[5]*hh[5]));
                    float md = fdot2u(tE.z, hhp0, fdot2u(tE.w, hhp1,
                               fdot2u(tF.x, hhp2, vv_[lr])));   // diag-folded + V seed
                    float nd = fdot2u(tF.y, hvh0, fdot2u(tF.z, hvh1,
                               fdot2u(tF.w, hvh2, 0.f)));       // diag-folded
                    acc[lr] = (ta + tb) + (md + nd);
                }

                // 4-lane reductions via DPP quad_perm
                float q0_ = acc[0]*acc[0], q1_ = acc[1]*acc[1], q2_ = acc[2]*acc[2];
                float ssl = (q0_ + q1_) + q2_;
                float pq  = fmaf(e2_[0], q0_, fmaf(e2_[1], q1_, e2_[2] * q2_));
                float s1  = ssl + DPPF(ssl, QP_XOR1);
                float ssq = s1 + DPPF(s1, QP_XOR2);
                float p1  = pq + DPPF(pq, QP_XOR1);
                float px  = DPPF(p1, QP_XOR2);
                const float inv = FAST_RSQ(ssq + 1e-12f);

                const int sel = (cbr >> qq) & 1;
                const float qsel = (mya == sel) ? p1 : px;
                amp2 *= qsel * FAST_RCP(p1 + px);

                float an0 = acc[0] * inv, an1 = acc[1] * inv, an2 = acc[2] * inv;
                float sw0 = DPPF(an0, QP_XOR2);
                float sw1 = DPPF(an1, QP_XOR2);
                float sw2 = DPPF(an2, QP_XOR2);
                an0 = sel ? sw0 : an0;
                an1 = sel ? sw1 : an1;
                an2 = sel ? sw2 : an2;
                hh[0] = DPPF(an0, QP_BC0); hh[3] = DPPF(an0, QP_BC1);
                hh[1] = DPPF(an1, QP_BC0); hh[4] = DPPF(an1, QP_BC1);
                hh[2] = DPPF(an2, QP_BC0); hh[5] = DPPF(an2, QP_BC1);
                hhp0 = pack2(hh[0], hh[1]);
                hhp1 = pack2(hh[2], hh[3]);
                hhp2 = pack2(hh[4], hh[5]);

                // phase via packed W dot2s (+ C seed)
                uint4 wv = Wl[slot];
                phi = fdot2u(wv.x, hhp0, fdot2u(wv.y, hhp1,
                      fdot2u(wv.z, hhp2, __uint_as_float(wv.w) + phi)));

                // vs write (skipped at qq==7: superseded by next row's qq==0)
                if (sub == 0 && qq != 7) {
                    *reinterpret_cast<uint4*>(vsm + j * 256 + s * 4) =
                        make_uint4(h2u(hhp0), h2u(hhp1), h2u(hhp2), 0u);
                }
            }
        }
    }

    if (sub == 0 && valid) {
        const float amp = sqrtf(amp2);
        if (writeImag) {
            out[2 * b + 0] = amp * cosf(phi);
            out[2 * b + 1] = amp * sinf(phi);
        } else {
            out[b] = amp * cosf(phi);
        }
    }
}

// ---------- fallback: exact r16 kernel (in-kernel staging) ------------------
__global__ __launch_bounds__(BT, 1) void mps_rnn16fb(
    const float* __restrict__ Mh, const float* __restrict__ Mv,
    const float* __restrict__ Vp, const float* __restrict__ Tp,
    const float* __restrict__ Wp, const float* __restrict__ Cp,
    const float* __restrict__ Ep, const int* __restrict__ X,
    float* __restrict__ out, int Bn, int writeImag)
{
    __shared__ unsigned Tl[16 * 12 * 24];
    __shared__ float    VE [16 * 4 * 8];
    __shared__ uint4    Wl [16];
    __shared__ unsigned vsm[8 * 64 * 4];

    const int t   = threadIdx.x;
    const int sub = t & 3;
    const int s   = t >> 2;
    int b = blockIdx.x * SPB + s;
    const bool valid = (b < Bn);
    if (!valid) b = Bn - 1;

    unsigned long long bits;
    {
        const int4* xr = reinterpret_cast<const int4*>(X + (size_t)b * NQ + sub * 16);
        unsigned long long part = 0ull;
        #pragma unroll
        for (int q = 0; q < 4; ++q) {
            int4 v = xr[q];
            part |= (unsigned long long)(v.x & 1) << (4 * q + 0);
            part |= (unsigned long long)(v.y & 1) << (4 * q + 1);
            part |= (unsigned long long)(v.z & 1) << (4 * q + 2);
            part |= (unsigned long long)(v.w & 1) << (4 * q + 3);
        }
        bits = part << (16 * sub);
        bits |= __shfl_xor(bits, 1, 64);
        bits |= __shfl_xor(bits, 2, 64);
    }
    for (int u = t; u < 8 * 64 * 4; u += BT) vsm[u] = 0u;
    const int mya = sub >> 1;
    float hh[6];
    h2v hhp0, hhp1, hhp2;
    float amp2 = 1.f, phi = 0.f;

    for (int ch = 0; ch < 4; ++ch) {
        __syncthreads();
        {
            const float2* gT = reinterpret_cast<const float2*>(Tp + ch * 6912);
            for (int p = t; p < 3456; p += BT) {
                int site = p / 216, rr = p - site * 216;
                int row = rr / 18,  w  = rr - row * 18;
                float2 v = gT[p];
                H2U hu; hu.hh = __floats2half2_rn(v.x, v.y);
                Tl[(site * 12 + row) * 24 + w] = hu.u;
            }
            const float2* gH = reinterpret_cast<const float2*>(Mh + ch * 1152);
            const float2* gV = reinterpret_cast<const float2*>(Mv + ch * 1152);
            for (int p = t; p < 576; p += BT) {
                int site = p / 36, rr = p - site * 36;
                int row = rr / 3,  w  = rr - row * 3;
                int o_r = row - ((row >= 6) ? 6 : 0);
                float2 vh = gH[p], vv2 = gV[p];
                if ((o_r >> 1) == w) {
                    if (o_r & 1) { vh.y += 1.f; vv2.y += 1.f; }
                    else         { vh.x += 1.f; vv2.x += 1.f; }
                }
                H2U a; a.hh = __floats2half2_rn(vh.x, vh.y);
                H2U c; c.hh = __floats2half2_rn(vv2.x, vv2.y);
                Tl[(site * 12 + row) * 24 + 18 + w] = a.u;
                Tl[(site * 12 + row) * 24 + 21 + w] = c.u;
            }
            if (t < 192) {
                int site = t / 12, q = t - site * 12;
                int sb = q / 3,    c = q - sb * 3;
                VE[(site * 4 + sb) * 8 + c] = Vp[ch * 192 + t];
                float e = Ep[ch * 96 + site * 6 + (sb & 1) * 3 + c];
                VE[(site * 4 + sb) * 8 + 3 + c] = e * e;
            } else if (t < 208) {
                int site = t - 192;
                const float2* gw = reinterpret_cast<const float2*>(Wp) + ch * 48 + site * 3;
                float2 w01 = gw[0], w23 = gw[1], w45 = gw[2];
                H2U u0, u1, u2;
                u0.hh = __floats2half2_rn(w01.x, w01.y);
                u1.hh = __floats2half2_rn(w23.x, w23.y);
                u2.hh = __floats2half2_rn(w45.x, w45.y);
                Wl[site] = make_uint4(u0.u, u1.u, u2.u,
                                      __float_as_uint(Cp[ch * 16 + site]));
            }
        }
        __syncthreads();

        #pragma unroll
        for (int ih = 0; ih < 2; ++ih) {
            const unsigned cbr = (unsigned)(bits >> (ch * 16 + ih * 8)) & 0xFFu;
            #pragma unroll 2
            for (int qq = 0; qq < 8; ++qq) {
                const int j    = ih ? 7 - qq : qq;
                const int slot = ih * 8 + j;
                const unsigned* Tb = Tl + (slot * 12 + sub * 3) * 24;
                const float*   VEb = VE + (slot * 4 + sub) * 8;
                if (qq == 0) {
                    #pragma unroll
                    for (int o = 0; o < 6; ++o) hh[o] = 1.f;
                    H2U one; one.u = 0x3C003C00u;
                    hhp0 = one.h; hhp1 = one.h; hhp2 = one.h;
                }
                uint4 hvu = *reinterpret_cast<const uint4*>(vsm + j * 256 + s * 4);
                const h2v hvh0 = u2h(hvu.x);
                const h2v hvh1 = u2h(hvu.y);
                const h2v hvh2 = u2h(hvu.z);
                float4 ve0 = *reinterpret_cast<const float4*>(VEb);
                float2 ve1 = *reinterpret_cast<const float2*>(VEb + 4);
                const float vv_[3] = { ve0.x, ve0.y, ve0.z };
                const float e2_[3] = { ve0.w, ve1.x, ve1.y };
                float acc[3];
                #pragma unroll
                for (int lr = 0; lr < 3; ++lr) {
                    const unsigned* Tr = Tb + lr * 24;
                    uint4 tA = *reinterpret_cast<const uint4*>(Tr);
                    uint4 tB = *reinterpret_cast<const uint4*>(Tr + 4);
                    uint4 tC = *reinterpret_cast<const uint4*>(Tr + 8);
                    uint4 tD = *reinterpret_cast<const uint4*>(Tr + 12);
                    uint4 tE = *reinterpret_cast<const uint4*>(Tr + 16);
                    uint4 tF = *reinterpret_cast<const uint4*>(Tr + 20);
                    const unsigned tw[18] = {tA.x,tA.y,tA.z,tA.w, tB.x,tB.y,tB.z,tB.w,
                                             tC.x,tC.y,tC.z,tC.w, tD.x,tD.y,tD.z,tD.w,
                                             tE.x,tE.y};
                    float sc[6];
                    #pragma unroll
                    for (int c = 0; c < 6; ++c)
                        sc[c] = fdot2u(tw[c*3+0], hvh0,
                                fdot2u(tw[c*3+1], hvh1,
                                fdot2u(tw[c*3+2], hvh2, 0.f)));
                    float ta = fmaf(sc[0], hh[0], fmaf(sc[2], hh[2], sc[4]*hh[4]));
                    float tb = fmaf(sc[1], hh[1], fmaf(sc[3], hh[3], sc[5]*hh[5]));
                    float md = fdot2u(tE.z, hhp0, fdot2u(tE.w, hhp1,
                               fdot2u(tF.x, hhp2, vv_[lr])));
                    float nd = fdot2u(tF.y, hvh0, fdot2u(tF.z, hvh1,
                               fdot2u(tF.w, hvh2, 0.f)));
                    acc[lr] = (ta + tb) + (md + nd);
                }
                float q0_ = acc[0]*acc[0], q1_ = acc[1]*acc[1], q2_ = acc[2]*acc[2];
                float ssl = (q0_ + q1_) + q2_;
                float pq  = fmaf(e2_[0], q0_, fmaf(e2_[1], q1_, e2_[2] * q2_));
                float s1  = ssl + DPPF(ssl, QP_XOR1);
                float ssq = s1 + DPPF(s1, QP_XOR2);
                float p1  = pq + DPPF(pq, QP_XOR1);
                float px  = DPPF(p1, QP_XOR2);
                const float inv = FAST_RSQ(ssq + 1e-12f);
                const int sel = (cbr >> qq) & 1;
                const float qsel = (mya == sel) ? p1 : px;
                amp2 *= qsel * FAST_RCP(p1 + px);
                float an0 = acc[0] * inv, an1 = acc[1] * inv, an2 = acc[2] * inv;
                float sw0 = DPPF(an0, QP_XOR2);
                float sw1 = DPPF(an1, QP_XOR2);
                float sw2 = DPPF(an2, QP_XOR2);
                an0 = sel ? sw0 : an0;
                an1 = sel ? sw1 : an1;
                an2 = sel ? sw2 : an2;
                hh[0] = DPPF(an0, QP_BC0); hh[3] = DPPF(an0, QP_BC1);
                hh[1] = DPPF(an1, QP_BC0); hh[4] = DPPF(an1, QP_BC1);
                hh[2] = DPPF(an2, QP_BC0); hh[5] = DPPF(an2, QP_BC1);
                hhp0 = pack2(hh[0], hh[1]);
                hhp1 = pack2(hh[2], hh[3]);
                hhp2 = pack2(hh[4], hh[5]);
                uint4 wv = Wl[slot];
                phi = fdot2u(wv.x, hhp0, fdot2u(wv.y, hhp1,
                      fdot2u(wv.z, hhp2, __uint_as_float(wv.w) + phi)));
                if (sub == 0) {
                    *reinterpret_cast<uint4*>(vsm + j * 256 + s * 4) =
                        make_uint4(h2u(hhp0), h2u(hhp1), h2u(hhp2), 0u);
                }
            }
        }
    }

    if (sub == 0 && valid) {
        const float amp = sqrtf(amp2);
        if (writeImag) {
            out[2 * b + 0] = amp * cosf(phi);
            out[2 * b + 1] = amp * sinf(phi);
        } else {
            out[b] = amp * cosf(phi);
        }
    }
}

extern "C" void kernel_launch(void* const* d_in, const int* in_sizes, int n_in,
                              void* d_out, int out_size, void* d_ws, size_t ws_size,
                              hipStream_t stream) {
    const float* Mh = (const float*)d_in[0];
    const float* Mv = (const float*)d_in[1];
    const float* Vp = (const float*)d_in[2];
    const float* Tp = (const float*)d_in[3];
    const float* Wp = (const float*)d_in[4];
    const float* Cp = (const float*)d_in[5];
    const float* Ep = (const float*)d_in[6];
    const int*   X  = (const int*)d_in[7];
    float* out = (float*)d_out;

    const int Bn = in_sizes[7] / NQ;                 // 32768
    const int writeImag = (out_size >= 2 * Bn) ? 1 : 0;
    const int grid = (Bn + SPB - 1) / SPB;           // 512 blocks of 256 threads

    const size_t need = (size_t)4 * CHUNK_U * sizeof(unsigned);  // 82944 B
    if (ws_size >= need) {
        repack_k<<<4, BT, 0, stream>>>(Mh, Mv, Vp, Tp, Wp, Cp, Ep,
                                       (unsigned*)d_ws);
        mps_rnn20<<<grid, BT, 0, stream>>>((const unsigned*)d_ws, X, out,
                                           Bn, writeImag);
    } else {
        mps_rnn16fb<<<grid, BT, 0, stream>>>(Mh, Mv, Vp, Tp, Wp, Cp, Ep, X,
                                             out, Bn, writeImag);
    }
}